// Round 11
// baseline (524.662 us; speedup 1.0000x reference)
//
#include <hip/hip_runtime.h>
#include <hip/hip_bf16.h>

// ---------------------------------------------------------------------------
// Swin shifted-window attention, fully fused per-window kernel.
//   x:[8,128,128,256] f32, w_qkv:[256,768], pos:[15,15], w_out:[256,256], b_out:[256]
//   out:[8,128,128,256] f32
// R11: one block = one window; 1024 threads = 16 waves; wave (h, half)
// handles query-token-tile `half` (32 tokens) of head h. K/V projections are
// duplicated across the (h,0)/(h,1) wave pair (identical weight addresses ->
// L1 hits; MFMA issue slots were 84% idle). All matmuls 32x32x16 bf16 MFMA.
//
// Journal:
//  R1: fused 8-wave kernel, 64KB LDS                         -> PASS 231 us
//  R2: bounds(512,6) = 40-reg cap                            -> PASS 1873 us (spill)
//  R3: inline-asm permlane makefrag                          -> FAIL NaN
//  R5: + Btab C-init/early-conv/deferred-sum                 -> PASS 239 us
//  R7: sequential Q->K->V                                    -> PASS 225 us
//  R8: fragment-ordered coalesced weight/bias packs          -> PASS 166 us
//  R9: softmax before V (AGPR peak 96->64)                   -> PASS 166 us (=R8)
//  R10: bi-sequential S + merged QK pass                     -> PASS 163 us
//      R8-R10 all 128V+AGPR>128 total -> 1 block/CU (22% occ). 8-wave blocks
//      have no intermediate occupancy step; BW MLP-limited at 1.1 TB/s and
//      dur ~= 214MB/1.1TBps. Occupancy IS the lever.
//  R11: 16-wave split-half blocks + launch_bounds(1024,1) FORCES <=128 total
//      (4 waves/SIMD). Per-wave state ~halved. Target 16 waves/CU.
//
// MFMA 32x32x16 layouts (verified R1-R10):
//   A-frag: lane l supplies A[m = l%32][k = 8*(l>>5)+i], i=0..7
//   B-frag: lane l supplies B[k = 8*(l>>5)+i][n = l%32]
//   C/D   : (row,col): col = l&31, row = (reg&3) + 8*(reg>>2) + 4*(l>>5)
// ---------------------------------------------------------------------------

typedef __attribute__((ext_vector_type(8)))  short bf16x8;
typedef __attribute__((ext_vector_type(16))) float f32x16;

#define MFMA32(a, b, c) __builtin_amdgcn_mfma_f32_32x32x16_bf16((a), (b), (c), 0, 0, 0)

#define QK_SCALE 0.17677669529663687f  // 1/sqrt(32)
#define LOG2E    1.44269504088896340f

__device__ __forceinline__ uint32_t pack2(float lo, float hi) {
  uint32_t l = (uint32_t)__bfloat16_as_ushort(__float2bfloat16(lo));
  uint32_t h = (uint32_t)__bfloat16_as_ushort(__float2bfloat16(hi));
  return l | (h << 16);
}

__device__ __forceinline__ bf16x8 frag_from_u4(uint32_t a, uint32_t b,
                                               uint32_t c, uint32_t d) {
  union { uint32_t u[4]; bf16x8 v; } r;
  r.u[0] = a; r.u[1] = b; r.u[2] = c; r.u[3] = d;
  return r.v;
}

// Fragment re-pack from a 32x32 accumulator: k walks acc ROW index, m/n = col.
// PROVEN shfl_xor form (R1-R10); inline-asm permlane NaN'd in R3.
__device__ __forceinline__ bf16x8 makefrag(const f32x16& a, int kt, int hf) {
  const int b0 = kt * 8;
  uint32_t q0 = pack2(a[b0 + 0], a[b0 + 1]);
  uint32_t q1 = pack2(a[b0 + 2], a[b0 + 3]);
  uint32_t q2 = pack2(a[b0 + 4], a[b0 + 5]);
  uint32_t q3 = pack2(a[b0 + 6], a[b0 + 7]);
  uint32_t x0 = (uint32_t)__shfl_xor((int)q0, 32, 64);
  uint32_t x1 = (uint32_t)__shfl_xor((int)q1, 32, 64);
  uint32_t x2 = (uint32_t)__shfl_xor((int)q2, 32, 64);
  uint32_t x3 = (uint32_t)__shfl_xor((int)q3, 32, 64);
  uint32_t d0 = hf ? x2 : q0;
  uint32_t d1 = hf ? x3 : q1;
  uint32_t d2 = hf ? q2 : x0;
  uint32_t d3 = hf ? q3 : x1;
  return frag_from_u4(d0, d1, d2, d3);
}

// ---------------------------------------------------------------------------
// Prep: FRAGMENT-ORDERED packs (unchanged from R8-R10).
//  Wpack  [sec(3: q,k,v)][h(8)][kt(16)][lane(64)][i(8)] bf16
//  WoPack [h][kt][lane][i] bf16
//  Bpack  [type(4)][ai(2)][bi(2)][rb(4)][lane(64)][j(4)] f32
// ---------------------------------------------------------------------------
__global__ void prep_weights(const float* __restrict__ wqkv,
                             const float* __restrict__ wout,
                             const float* __restrict__ pos,
                             ushort* __restrict__ Wpack,
                             ushort* __restrict__ WoPack,
                             float* __restrict__ Bpack) {
  int id = blockIdx.x * 256 + threadIdx.x;
  if (id < 196608) {                       // 3*8*16*64*8
    int sec = id >> 16;
    int j = id & 65535;
    int h = j >> 13, kt = (j >> 9) & 15, lane = (j >> 3) & 63, i = j & 7;
    int n = h * 32 + (lane & 31);
    int k = kt * 16 + (lane >> 5) * 8 + i;
    float v = wqkv[k * 768 + sec * 256 + n];
    if (sec == 0) v *= QK_SCALE;
    Wpack[id] = __bfloat16_as_ushort(__float2bfloat16(v));
  } else if (id < 262144) {                // + 8*16*64*8
    int j = id - 196608;
    int h = j >> 13, kt = (j >> 9) & 15, lane = (j >> 3) & 63, i = j & 7;
    int n = h * 32 + (lane & 31);
    int k = kt * 16 + (lane >> 5) * 8 + i;
    WoPack[j] = __bfloat16_as_ushort(__float2bfloat16(wout[k * 256 + n]));
  } else if (id < 278528) {                // + 4*2*2*4*64*4
    int j = id - 262144;
    int type = j >> 12;
    int r12 = j & 4095;
    int ai = r12 >> 11, bi = (r12 >> 10) & 1, rb = (r12 >> 8) & 3;
    int lane = (r12 >> 2) & 63, jj = r12 & 3;
    int n = jj + 8 * rb + 4 * (lane >> 5) + 32 * ai;
    int m = (lane & 31) + 32 * bi;
    float v = pos[((n >> 3) - (m >> 3) + 7) * 15 + ((n & 7) - (m & 7) + 7)];
    bool ul = (m >= 32) != (n >= 32);
    bool lr = ((m & 7) >= 4) != ((n & 7) >= 4);
    if (((type & 2) && ul) || ((type & 1) && lr)) v = -1e30f;
    Bpack[j] = v;
  }
}

// ---------------------------------------------------------------------------
__global__ __launch_bounds__(1024, 1) void swin_attn(
    const float* __restrict__ x, const float* __restrict__ bout,
    const ushort* __restrict__ Wpack, const ushort* __restrict__ WoPack,
    const float* __restrict__ Bpack, float* __restrict__ out) {
  // 32 KB union buffer: phases 0-2 x-window bf16 (k-grouped, swizzled);
  // phases 3-4 O^T bf16 (same k-grouped slot layout, k = h*32+d).
  __shared__ uint4 lds[32 * 64];
  uint4*  ldsX = lds;
  ushort* ldsO = (ushort*)lds;

  const int bid = blockIdx.x;
  const int b  = bid >> 8;
  const int wy = (bid >> 4) & 15;
  const int wx = bid & 15;
  const int t    = threadIdx.x;
  const int lane = t & 63;
  const int w    = t >> 6;                 // wave id 0..15
  const int h    = w >> 1;                 // head
  const int half = w & 1;                  // query-token tile (0: tok 0-31)
  const int l31  = lane & 31;
  const int hf   = lane >> 5;

  f32x16 zf;
  #pragma unroll
  for (int i = 0; i < 16; ++i) zf[i] = 0.0f;

  // ---- stage shifted x window -> LDS bf16 (1024 threads, 2 slots each) --
  {
    int tok = t >> 4, kc = t & 15;
    int ty = tok >> 3, tx = tok & 7;
    int yy = (wy * 8 + ty + 4) & 127;      // roll(-4,-4) folded into read
    int xx = (wx * 8 + tx + 4) & 127;
    const float* xr = x + (((b * 128 + yy) * 128 + xx) << 8);
    #pragma unroll
    for (int gg = 0; gg < 2; ++gg) {
      int kg = kc * 2 + gg;
      float4 a = *(const float4*)(xr + kg * 8);
      float4 c = *(const float4*)(xr + kg * 8 + 4);
      uint4 wv;
      wv.x = pack2(a.x, a.y); wv.y = pack2(a.z, a.w);
      wv.z = pack2(c.x, c.y); wv.w = pack2(c.z, c.w);
      ldsX[(kg * 64 + tok) ^ (kg >> 2)] = wv;
    }
  }
  __syncthreads();

  // Per-head fragment-ordered weight bases (1KB contiguous per wave-load).
  const ushort* wqp = Wpack + h * 8192;            // [kt][lane][8]
  const ushort* wkp = wqp + 65536;
  const ushort* wvp = wkp + 65536;

  // ---- merged Q+K pass: Q only for this half's tokens; K for all 64 -----
  bf16x8 fQ[2], fK[2][2];
  {
    f32x16 aq = zf, ak0 = zf, ak1 = zf;
    #pragma unroll
    for (int kt = 0; kt < 16; ++kt) {
      int kg = 2 * kt + hf;
      uint4 ux0 = ldsX[(kg * 64 + l31) ^ (kg >> 2)];
      uint4 ux1 = ldsX[(kg * 64 + 32 + l31) ^ (kg >> 2)];
      bf16x8 xf0 = frag_from_u4(ux0.x, ux0.y, ux0.z, ux0.w);
      bf16x8 xf1 = frag_from_u4(ux1.x, ux1.y, ux1.z, ux1.w);
      bf16x8 xq  = half ? xf1 : xf0;       // wave-uniform select
      bf16x8 fwq = *(const bf16x8*)(wqp + kt * 512 + lane * 8);
      bf16x8 fwk = *(const bf16x8*)(wkp + kt * 512 + lane * 8);
      aq  = MFMA32(fwq, xq,  aq);
      ak0 = MFMA32(fwk, xf0, ak0);
      ak1 = MFMA32(fwk, xf1, ak1);
    }
    #pragma unroll
    for (int kt = 0; kt < 2; ++kt) {
      fQ[kt]    = makefrag(aq,  kt, hf);
      fK[0][kt] = makefrag(ak0, kt, hf);
      fK[1][kt] = makefrag(ak1, kt, hf);
    }
  }

  // ---- S^T (keys x this half's queries), C-init from Bpack; softmax -----
  const float* Bp = Bpack + ((((wy == 15) ? 2 : 0) | ((wx == 15) ? 1 : 0)) << 12);
  bf16x8 pf[4];
  float ri;
  {
    f32x16 s0, s1;                         // key tiles ai=0,1
    #pragma unroll
    for (int rb = 0; rb < 4; ++rb) {
      float4 f0 = *(const float4*)(Bp + ((half * 4 + rb) * 64 + lane) * 4);
      float4 f1 = *(const float4*)(Bp + (((2 + half) * 4 + rb) * 64 + lane) * 4);
      s0[rb * 4 + 0] = f0.x; s0[rb * 4 + 1] = f0.y;
      s0[rb * 4 + 2] = f0.z; s0[rb * 4 + 3] = f0.w;
      s1[rb * 4 + 0] = f1.x; s1[rb * 4 + 1] = f1.y;
      s1[rb * 4 + 2] = f1.z; s1[rb * 4 + 3] = f1.w;
    }
    #pragma unroll
    for (int kt = 0; kt < 2; ++kt) {
      s0 = MFMA32(fK[0][kt], fQ[kt], s0);
      s1 = MFMA32(fK[1][kt], fQ[kt], s1);
    }
    float mx = -3e38f;
    #pragma unroll
    for (int r = 0; r < 16; ++r) mx = fmaxf(mx, fmaxf(s0[r], s1[r]));
    mx = fmaxf(mx, __shfl_xor(mx, 32, 64));
    float sum = 0.0f;
    #pragma unroll
    for (int r = 0; r < 16; ++r) {
      float p0 = exp2f((s0[r] - mx) * LOG2E);
      float p1 = exp2f((s1[r] - mx) * LOG2E);
      s0[r] = p0; s1[r] = p1;
      sum += p0 + p1;
    }
    sum += __shfl_xor(sum, 32, 64);
    ri = 1.0f / sum;                       // deferred to ot scale
    #pragma unroll
    for (int kt = 0; kt < 2; ++kt) {
      pf[kt]     = makefrag(s0, kt, hf);
      pf[2 + kt] = makefrag(s1, kt, hf);
    }
  }

  // ---- pass V: V = X · Wv (all 64 key tokens; fQ/fK dead) ---------------
  bf16x8 fV[2][2];
  {
    f32x16 a0 = zf, a1 = zf;
    #pragma unroll
    for (int kt = 0; kt < 16; ++kt) {
      int kg = 2 * kt + hf;
      uint4 ux0 = ldsX[(kg * 64 + l31) ^ (kg >> 2)];
      uint4 ux1 = ldsX[(kg * 64 + 32 + l31) ^ (kg >> 2)];
      bf16x8 xf0 = frag_from_u4(ux0.x, ux0.y, ux0.z, ux0.w);
      bf16x8 xf1 = frag_from_u4(ux1.x, ux1.y, ux1.z, ux1.w);
      bf16x8 fw = *(const bf16x8*)(wvp + kt * 512 + lane * 8);
      a0 = MFMA32(xf0, fw, a0);  a1 = MFMA32(xf1, fw, a1);
    }
    #pragma unroll
    for (int kt = 0; kt < 2; ++kt) {
      fV[0][kt] = makefrag(a0, kt, hf);
      fV[1][kt] = makefrag(a1, kt, hf);
    }
  }

  // ---- O^T = V^T · P^T (rows=d, cols=this half's 32 queries) ------------
  f32x16 ot = zf;
  #pragma unroll
  for (int jt = 0; jt < 4; ++jt)
    ot = MFMA32(fV[jt >> 1][jt & 1], pf[jt], ot);
  #pragma unroll
  for (int r = 0; r < 16; ++r) ot[r] *= ri;

  // all waves must be done reading ldsX before ldsO overwrites the union
  __syncthreads();

  // ---- O^T -> LDS bf16 (k = h*32 + d, k-grouped slots) ------------------
  {
    int tok = half * 32 + l31;
    #pragma unroll
    for (int g = 0; g < 4; ++g) {
      int kg = h * 4 + g;                  // d = 8g + 4hf + 0..3
      uint2 wv2;
      wv2.x = pack2(ot[4 * g + 0], ot[4 * g + 1]);
      wv2.y = pack2(ot[4 * g + 2], ot[4 * g + 3]);
      *(uint2*)&ldsO[(kg * 64 + tok) * 8 + 4 * hf] = wv2;
    }
  }
  __syncthreads();

  // ---- out-proj: wave (h,half) -> out cols h*32..+31, its 32 tokens -----
  const ushort* wop = WoPack + h * 8192;
  f32x16 u = zf;
  #pragma unroll
  for (int kt = 0; kt < 16; ++kt) {
    int kg = 2 * kt + hf;
    bf16x8 wa = *(const bf16x8*)(wop + kt * 512 + lane * 8);
    bf16x8 bb = *(const bf16x8*)&ldsO[(kg * 64 + half * 32 + l31) * 8];
    u = MFMA32(wa, bb, u);
  }

  // ---- epilogue: + b_out, write fp32 with roll(+4,+4) folded in ---------
  {
    int tok = half * 32 + l31;
    int ty = tok >> 3, tx = tok & 7;
    int yy = (wy * 8 + ty + 4) & 127;
    int xx = (wx * 8 + tx + 4) & 127;
    float* ob = out + (((b * 128 + yy) * 128 + xx) << 8);
    #pragma unroll
    for (int g = 0; g < 4; ++g) {
      int c0 = h * 32 + 8 * g + 4 * hf;
      float4 bo = *(const float4*)(bout + c0);
      float4 v;
      v.x = u[4 * g + 0] + bo.x;
      v.y = u[4 * g + 1] + bo.y;
      v.z = u[4 * g + 2] + bo.z;
      v.w = u[4 * g + 3] + bo.w;
      *(float4*)(ob + c0) = v;
    }
  }
}

// ---------------------------------------------------------------------------
extern "C" void kernel_launch(void* const* d_in, const int* in_sizes, int n_in,
                              void* d_out, int out_size, void* d_ws, size_t ws_size,
                              hipStream_t stream) {
  const float* x    = (const float*)d_in[0];
  const float* wqkv = (const float*)d_in[1];
  const float* pos  = (const float*)d_in[2];
  const float* wout = (const float*)d_in[3];
  const float* bout = (const float*)d_in[4];

  ushort* Wpack  = (ushort*)d_ws;                     // [3][8][16][64][8] bf16
  ushort* WoPack = Wpack + 196608;                    // [8][16][64][8] bf16
  float*  Bpack  = (float*)((char*)d_ws + 524288);    // [4][2][2][4][64][4] f32

  prep_weights<<<1088, 256, 0, stream>>>(wqkv, wout, pos, Wpack, WoPack, Bpack);
  swin_attn<<<2048, 1024, 0, stream>>>(x, bout, Wpack, WoPack, Bpack, (float*)d_out);
}

// Round 12
// 237.352 us; speedup vs baseline: 2.2105x; 2.2105x over previous
//
#include <hip/hip_runtime.h>
#include <hip/hip_bf16.h>

// ---------------------------------------------------------------------------
// Swin shifted-window attention, fused per-(window,query-half) kernel.
//   x:[8,128,128,256] f32, w_qkv:[256,768], pos:[15,15], w_out:[256,256], b_out:[256]
//   out:[8,128,128,256] f32
// R12: one block = (window, query-half): 512 threads = 8 waves = 8 heads,
// each wave computes its head for 32 query tokens. K/V are computed for all
// 64 tokens in BOTH half-blocks (duplicate MFMA work; issue slots were 84%
// idle). 2 blocks/window -> grid 4096. Per-wave register peak ~110 total
// (vs ~160 in R10) -> target 4 waves/SIMD (2 blocks/CU, 50% occ).
//
// Journal:
//  R1:  fused 8-wave kernel                                  -> PASS 231 us
//  R2:  bounds(512,6) -> compiler capped 40 regs             -> PASS 1873 us (spill)
//  R3:  inline-asm permlane makefrag                         -> FAIL NaN
//  R5:  + Bpack C-init/early-conv/deferred-sum               -> PASS 239 us
//  R7:  sequential Q->K->V                                   -> PASS 225 us
//  R8:  fragment-ordered coalesced packs                     -> PASS 166 us
//  R9:  softmax before V                                     -> PASS 166 us (=R8)
//  R10: bi-sequential S + merged QK                          -> PASS 163 us
//       R8-R10: 128V+~32A=160 total -> 2 waves/SIMD (22% occ). Reg-file
//       model: waves/SIMD x total-regs <= 512 (m69).
//  R11: 16-wave blocks + bounds(1024,1): compiler chose 64-reg cap -> 1.9 GB
//       spill traffic -> 525 us. launch_bounds arg2 is UNRELIABLE for
//       forcing caps. But half-split per-wave math verified (absmax 9.8e-4)
//       and its true state ledger ~110 regs.
//  R12: R11 math in 512-thread half-blocks, benign (512,2). No forced cap.
//
// MFMA 32x32x16 layouts (verified R1-R11):
//   A-frag: lane l supplies A[m = l%32][k = 8*(l>>5)+i], i=0..7
//   B-frag: lane l supplies B[k = 8*(l>>5)+i][n = l%32]
//   C/D   : (row,col): col = l&31, row = (reg&3) + 8*(reg>>2) + 4*(l>>5)
// ---------------------------------------------------------------------------

typedef __attribute__((ext_vector_type(8)))  short bf16x8;
typedef __attribute__((ext_vector_type(16))) float f32x16;

#define MFMA32(a, b, c) __builtin_amdgcn_mfma_f32_32x32x16_bf16((a), (b), (c), 0, 0, 0)

#define QK_SCALE 0.17677669529663687f  // 1/sqrt(32)
#define LOG2E    1.44269504088896340f

__device__ __forceinline__ uint32_t pack2(float lo, float hi) {
  uint32_t l = (uint32_t)__bfloat16_as_ushort(__float2bfloat16(lo));
  uint32_t h = (uint32_t)__bfloat16_as_ushort(__float2bfloat16(hi));
  return l | (h << 16);
}

__device__ __forceinline__ bf16x8 frag_from_u4(uint32_t a, uint32_t b,
                                               uint32_t c, uint32_t d) {
  union { uint32_t u[4]; bf16x8 v; } r;
  r.u[0] = a; r.u[1] = b; r.u[2] = c; r.u[3] = d;
  return r.v;
}

// Fragment re-pack from a 32x32 accumulator: k walks acc ROW index, m/n = col.
// PROVEN shfl_xor form (R1-R11); inline-asm permlane NaN'd in R3.
__device__ __forceinline__ bf16x8 makefrag(const f32x16& a, int kt, int hf) {
  const int b0 = kt * 8;
  uint32_t q0 = pack2(a[b0 + 0], a[b0 + 1]);
  uint32_t q1 = pack2(a[b0 + 2], a[b0 + 3]);
  uint32_t q2 = pack2(a[b0 + 4], a[b0 + 5]);
  uint32_t q3 = pack2(a[b0 + 6], a[b0 + 7]);
  uint32_t x0 = (uint32_t)__shfl_xor((int)q0, 32, 64);
  uint32_t x1 = (uint32_t)__shfl_xor((int)q1, 32, 64);
  uint32_t x2 = (uint32_t)__shfl_xor((int)q2, 32, 64);
  uint32_t x3 = (uint32_t)__shfl_xor((int)q3, 32, 64);
  uint32_t d0 = hf ? x2 : q0;
  uint32_t d1 = hf ? x3 : q1;
  uint32_t d2 = hf ? q2 : x0;
  uint32_t d3 = hf ? q3 : x1;
  return frag_from_u4(d0, d1, d2, d3);
}

// ---------------------------------------------------------------------------
// Prep: FRAGMENT-ORDERED packs (unchanged from R8-R11).
//  Wpack  [sec(3: q,k,v)][h(8)][kt(16)][lane(64)][i(8)] bf16
//  WoPack [h][kt][lane][i] bf16
//  Bpack  [type(4)][ai(2)][bi(2)][rb(4)][lane(64)][j(4)] f32
// ---------------------------------------------------------------------------
__global__ void prep_weights(const float* __restrict__ wqkv,
                             const float* __restrict__ wout,
                             const float* __restrict__ pos,
                             ushort* __restrict__ Wpack,
                             ushort* __restrict__ WoPack,
                             float* __restrict__ Bpack) {
  int id = blockIdx.x * 256 + threadIdx.x;
  if (id < 196608) {                       // 3*8*16*64*8
    int sec = id >> 16;
    int j = id & 65535;
    int h = j >> 13, kt = (j >> 9) & 15, lane = (j >> 3) & 63, i = j & 7;
    int n = h * 32 + (lane & 31);
    int k = kt * 16 + (lane >> 5) * 8 + i;
    float v = wqkv[k * 768 + sec * 256 + n];
    if (sec == 0) v *= QK_SCALE;
    Wpack[id] = __bfloat16_as_ushort(__float2bfloat16(v));
  } else if (id < 262144) {                // + 8*16*64*8
    int j = id - 196608;
    int h = j >> 13, kt = (j >> 9) & 15, lane = (j >> 3) & 63, i = j & 7;
    int n = h * 32 + (lane & 31);
    int k = kt * 16 + (lane >> 5) * 8 + i;
    WoPack[j] = __bfloat16_as_ushort(__float2bfloat16(wout[k * 256 + n]));
  } else if (id < 278528) {                // + 4*2*2*4*64*4
    int j = id - 262144;
    int type = j >> 12;
    int r12 = j & 4095;
    int ai = r12 >> 11, bi = (r12 >> 10) & 1, rb = (r12 >> 8) & 3;
    int lane = (r12 >> 2) & 63, jj = r12 & 3;
    int n = jj + 8 * rb + 4 * (lane >> 5) + 32 * ai;
    int m = (lane & 31) + 32 * bi;
    float v = pos[((n >> 3) - (m >> 3) + 7) * 15 + ((n & 7) - (m & 7) + 7)];
    bool ul = (m >= 32) != (n >= 32);
    bool lr = ((m & 7) >= 4) != ((n & 7) >= 4);
    if (((type & 2) && ul) || ((type & 1) && lr)) v = -1e30f;
    Bpack[j] = v;
  }
}

// ---------------------------------------------------------------------------
__global__ __launch_bounds__(512, 2) void swin_attn(
    const float* __restrict__ x, const float* __restrict__ bout,
    const ushort* __restrict__ Wpack, const ushort* __restrict__ WoPack,
    const float* __restrict__ Bpack, float* __restrict__ out) {
  // 32 KB union: phases 0-2 x-window bf16 (k-grouped, swizzled);
  // phases 3-4 O^T bf16 for THIS HALF's 32 tokens (16 KB, k = h*32+d).
  __shared__ uint4 lds[32 * 64];
  uint4*  ldsX = lds;
  ushort* ldsO = (ushort*)lds;

  const int bid  = blockIdx.x;
  const int b    = bid >> 9;
  const int wy   = (bid >> 5) & 15;
  const int wx   = (bid >> 1) & 15;
  const int half = bid & 1;                // query-token tile (0: tok 0-31)
  const int t    = threadIdx.x;
  const int lane = t & 63;
  const int h    = t >> 6;                 // wave id == head id
  const int l31  = lane & 31;
  const int hf   = lane >> 5;

  f32x16 zf;
  #pragma unroll
  for (int i = 0; i < 16; ++i) zf[i] = 0.0f;

  // ---- stage shifted x window -> LDS bf16 (full 64 tokens: K/V need all) -
  {
    int tok = t >> 3, kc = t & 7;
    int ty = tok >> 3, tx = tok & 7;
    int yy = (wy * 8 + ty + 4) & 127;      // roll(-4,-4) folded into read
    int xx = (wx * 8 + tx + 4) & 127;
    const float* xr = x + (((b * 128 + yy) * 128 + xx) << 8) + kc * 32;
    #pragma unroll
    for (int g = 0; g < 4; ++g) {
      float4 a = *(const float4*)(xr + g * 8);
      float4 c = *(const float4*)(xr + g * 8 + 4);
      uint4 w;
      w.x = pack2(a.x, a.y); w.y = pack2(a.z, a.w);
      w.z = pack2(c.x, c.y); w.w = pack2(c.z, c.w);
      int kg = kc * 4 + g;
      ldsX[(kg * 64 + tok) ^ kc] = w;      // kc == kg>>2
    }
  }
  __syncthreads();

  // Per-head fragment-ordered weight bases (1KB contiguous per wave-load).
  const ushort* wqp = Wpack + h * 8192;            // [kt][lane][8]
  const ushort* wkp = wqp + 65536;
  const ushort* wvp = wkp + 65536;

  // ---- merged Q+K pass: Q only for this half's 32 tokens; K for all 64 --
  bf16x8 fQ[2], fK[2][2];
  {
    f32x16 aq = zf, ak0 = zf, ak1 = zf;
    #pragma unroll
    for (int kt = 0; kt < 16; ++kt) {
      int kg = 2 * kt + hf;
      uint4 ux0 = ldsX[(kg * 64 + l31) ^ (kg >> 2)];
      uint4 ux1 = ldsX[(kg * 64 + 32 + l31) ^ (kg >> 2)];
      bf16x8 xf0 = frag_from_u4(ux0.x, ux0.y, ux0.z, ux0.w);
      bf16x8 xf1 = frag_from_u4(ux1.x, ux1.y, ux1.z, ux1.w);
      bf16x8 xq  = half ? xf1 : xf0;       // block-uniform select
      bf16x8 fwq = *(const bf16x8*)(wqp + kt * 512 + lane * 8);
      bf16x8 fwk = *(const bf16x8*)(wkp + kt * 512 + lane * 8);
      aq  = MFMA32(fwq, xq,  aq);
      ak0 = MFMA32(fwk, xf0, ak0);
      ak1 = MFMA32(fwk, xf1, ak1);
    }
    #pragma unroll
    for (int kt = 0; kt < 2; ++kt) {
      fQ[kt]    = makefrag(aq,  kt, hf);
      fK[0][kt] = makefrag(ak0, kt, hf);
      fK[1][kt] = makefrag(ak1, kt, hf);
    }
  }

  // ---- S^T (all 64 keys x this half's 32 queries), C-init; softmax ------
  const float* Bp = Bpack + ((((wy == 15) ? 2 : 0) | ((wx == 15) ? 1 : 0)) << 12);
  bf16x8 pf[4];
  float ri;
  {
    f32x16 s0, s1;                         // key tiles ai=0,1
    #pragma unroll
    for (int rb = 0; rb < 4; ++rb) {
      float4 f0 = *(const float4*)(Bp + ((half * 4 + rb) * 64 + lane) * 4);
      float4 f1 = *(const float4*)(Bp + (((2 + half) * 4 + rb) * 64 + lane) * 4);
      s0[rb * 4 + 0] = f0.x; s0[rb * 4 + 1] = f0.y;
      s0[rb * 4 + 2] = f0.z; s0[rb * 4 + 3] = f0.w;
      s1[rb * 4 + 0] = f1.x; s1[rb * 4 + 1] = f1.y;
      s1[rb * 4 + 2] = f1.z; s1[rb * 4 + 3] = f1.w;
    }
    #pragma unroll
    for (int kt = 0; kt < 2; ++kt) {
      s0 = MFMA32(fK[0][kt], fQ[kt], s0);
      s1 = MFMA32(fK[1][kt], fQ[kt], s1);
    }
    float mx = -3e38f;
    #pragma unroll
    for (int r = 0; r < 16; ++r) mx = fmaxf(mx, fmaxf(s0[r], s1[r]));
    mx = fmaxf(mx, __shfl_xor(mx, 32, 64));
    float sum = 0.0f;
    #pragma unroll
    for (int r = 0; r < 16; ++r) {
      float p0 = exp2f((s0[r] - mx) * LOG2E);
      float p1 = exp2f((s1[r] - mx) * LOG2E);
      s0[r] = p0; s1[r] = p1;
      sum += p0 + p1;
    }
    sum += __shfl_xor(sum, 32, 64);
    ri = 1.0f / sum;                       // deferred to ot scale
    #pragma unroll
    for (int kt = 0; kt < 2; ++kt) {
      pf[kt]     = makefrag(s0, kt, hf);
      pf[2 + kt] = makefrag(s1, kt, hf);
    }
  }

  // ---- pass V: V = X · Wv (all 64 key tokens; fQ/fK dead) ---------------
  bf16x8 fV[2][2];
  {
    f32x16 a0 = zf, a1 = zf;
    #pragma unroll
    for (int kt = 0; kt < 16; ++kt) {
      int kg = 2 * kt + hf;
      uint4 ux0 = ldsX[(kg * 64 + l31) ^ (kg >> 2)];
      uint4 ux1 = ldsX[(kg * 64 + 32 + l31) ^ (kg >> 2)];
      bf16x8 xf0 = frag_from_u4(ux0.x, ux0.y, ux0.z, ux0.w);
      bf16x8 xf1 = frag_from_u4(ux1.x, ux1.y, ux1.z, ux1.w);
      bf16x8 fw = *(const bf16x8*)(wvp + kt * 512 + lane * 8);
      a0 = MFMA32(xf0, fw, a0);  a1 = MFMA32(xf1, fw, a1);
    }
    #pragma unroll
    for (int kt = 0; kt < 2; ++kt) {
      fV[0][kt] = makefrag(a0, kt, hf);
      fV[1][kt] = makefrag(a1, kt, hf);
    }
  }

  // ---- O^T = V^T · P^T (rows=d, cols=this half's 32 queries) ------------
  f32x16 ot = zf;
  #pragma unroll
  for (int jt = 0; jt < 4; ++jt)
    ot = MFMA32(fV[jt >> 1][jt & 1], pf[jt], ot);
  #pragma unroll
  for (int r = 0; r < 16; ++r) ot[r] *= ri;

  // all waves must be done reading ldsX before ldsO overwrites the union
  __syncthreads();

  // ---- O^T -> LDS bf16 (k = h*32 + d, 32-token slots) -------------------
  {
    #pragma unroll
    for (int g = 0; g < 4; ++g) {
      int kg = h * 4 + g;                  // d = 8g + 4hf + 0..3
      uint2 wv2;
      wv2.x = pack2(ot[4 * g + 0], ot[4 * g + 1]);
      wv2.y = pack2(ot[4 * g + 2], ot[4 * g + 3]);
      *(uint2*)&ldsO[(kg * 32 + l31) * 8 + 4 * hf] = wv2;
    }
  }
  __syncthreads();

  // ---- out-proj: wave h -> out cols h*32..+31 for this half's 32 tokens -
  const ushort* wop = WoPack + h * 8192;
  f32x16 u = zf;
  #pragma unroll
  for (int kt = 0; kt < 16; ++kt) {
    int kg = 2 * kt + hf;
    bf16x8 wa = *(const bf16x8*)(wop + kt * 512 + lane * 8);
    bf16x8 bb = *(const bf16x8*)&ldsO[(kg * 32 + l31) * 8];
    u = MFMA32(wa, bb, u);
  }

  // ---- epilogue: + b_out, write fp32 with roll(+4,+4) folded in ---------
  {
    int tok = half * 32 + l31;
    int ty = tok >> 3, tx = tok & 7;
    int yy = (wy * 8 + ty + 4) & 127;
    int xx = (wx * 8 + tx + 4) & 127;
    float* ob = out + (((b * 128 + yy) * 128 + xx) << 8);
    #pragma unroll
    for (int g = 0; g < 4; ++g) {
      int c0 = h * 32 + 8 * g + 4 * hf;
      float4 bo = *(const float4*)(bout + c0);
      float4 v;
      v.x = u[4 * g + 0] + bo.x;
      v.y = u[4 * g + 1] + bo.y;
      v.z = u[4 * g + 2] + bo.z;
      v.w = u[4 * g + 3] + bo.w;
      *(float4*)(ob + c0) = v;
    }
  }
}

// ---------------------------------------------------------------------------
extern "C" void kernel_launch(void* const* d_in, const int* in_sizes, int n_in,
                              void* d_out, int out_size, void* d_ws, size_t ws_size,
                              hipStream_t stream) {
  const float* x    = (const float*)d_in[0];
  const float* wqkv = (const float*)d_in[1];
  const float* pos  = (const float*)d_in[2];
  const float* wout = (const float*)d_in[3];
  const float* bout = (const float*)d_in[4];

  ushort* Wpack  = (ushort*)d_ws;                     // [3][8][16][64][8] bf16
  ushort* WoPack = Wpack + 196608;                    // [8][16][64][8] bf16
  float*  Bpack  = (float*)((char*)d_ws + 524288);    // [4][2][2][4][64][4] f32

  prep_weights<<<1088, 256, 0, stream>>>(wqkv, wout, pos, Wpack, WoPack, Bpack);
  swin_attn<<<4096, 512, 0, stream>>>(x, bout, Wpack, WoPack, Bpack, (float*)d_out);
}

// Round 14
// 139.310 us; speedup vs baseline: 3.7662x; 1.7038x over previous
//
#include <hip/hip_runtime.h>
#include <hip/hip_bf16.h>

// ---------------------------------------------------------------------------
// Swin shifted-window attention, fully fused per-window kernel.
//   x:[8,128,128,256] f32, w_qkv:[256,768], pos:[15,15], w_out:[256,256], b_out:[256]
//   out:[8,128,128,256] f32
// One block = one window; 512 threads = 8 waves = 8 heads. 32x32x16 bf16 MFMA.
//
// Journal:
//  R1:  fused 8-wave kernel                                  -> PASS 231 us
//  R2:  bounds(512,6): compiler 40-reg cap                   -> PASS 1873 us (spill)
//  R3:  inline-asm permlane makefrag                         -> FAIL NaN
//  R5:  + Bpack C-init/early-conv/deferred-sum               -> PASS 239 us
//  R7:  sequential Q->K->V                                   -> PASS 225 us
//  R8:  fragment-ordered coalesced packs                     -> PASS 166 us
//  R9:  softmax before V (AGPR 96->64)                       -> PASS 166 us (=R8)
//  R10: bi-sequential S (32A) + merged QK (48A)              -> PASS 163 us
//  R11: 16-wave + bounds(1024,1): 64-reg cap, 1.9GB spill    -> PASS 525 us
//  R12: half-split 512-thr blocks, K/V duplicated            -> PASS 237 us
//       VGPR 120 but merged-QK 48A -> total ~168 > 128 -> still 1 block/CU,
//       and 2x blocks doubled x FETCH (83->141MB). Duplication = pure cost.
//  MODEL: dur ~= 214MB / BW; BW ~= waves x inflight / latency. Occupancy
//       needs TOTAL V+A <= 128 for a 2nd 8-wave block. Blockers: (a) full
//       unroll hoists ~64V of weight loads, (b) merged phases hold >=48A.
//  R13: R10 minus QK-merge (seq Q,K: 32A peaks) + #pragma unroll 4 on all
//       16-iter loops (caps in-flight to ~16V). Ledger peak ~102-110 total.
//       -> infra failure (UnresponsiveContainer), never ran. R14 = resubmit.
//
// MFMA 32x32x16 layouts (verified R1-R12):
//   A-frag: lane l supplies A[m = l%32][k = 8*(l>>5)+i], i=0..7
//   B-frag: lane l supplies B[k = 8*(l>>5)+i][n = l%32]
//   C/D   : (row,col): col = l&31, row = (reg&3) + 8*(reg>>2) + 4*(l>>5)
// ---------------------------------------------------------------------------

typedef __attribute__((ext_vector_type(8)))  short bf16x8;
typedef __attribute__((ext_vector_type(16))) float f32x16;

#define MFMA32(a, b, c) __builtin_amdgcn_mfma_f32_32x32x16_bf16((a), (b), (c), 0, 0, 0)

#define QK_SCALE 0.17677669529663687f  // 1/sqrt(32)
#define LOG2E    1.44269504088896340f

__device__ __forceinline__ uint32_t pack2(float lo, float hi) {
  uint32_t l = (uint32_t)__bfloat16_as_ushort(__float2bfloat16(lo));
  uint32_t h = (uint32_t)__bfloat16_as_ushort(__float2bfloat16(hi));
  return l | (h << 16);
}

__device__ __forceinline__ bf16x8 frag_from_u4(uint32_t a, uint32_t b,
                                               uint32_t c, uint32_t d) {
  union { uint32_t u[4]; bf16x8 v; } r;
  r.u[0] = a; r.u[1] = b; r.u[2] = c; r.u[3] = d;
  return r.v;
}

// Fragment re-pack from a 32x32 accumulator: k walks acc ROW index, m/n = col.
// PROVEN shfl_xor form (R1-R12); inline-asm permlane NaN'd in R3.
__device__ __forceinline__ bf16x8 makefrag(const f32x16& a, int kt, int hf) {
  const int b0 = kt * 8;
  uint32_t q0 = pack2(a[b0 + 0], a[b0 + 1]);
  uint32_t q1 = pack2(a[b0 + 2], a[b0 + 3]);
  uint32_t q2 = pack2(a[b0 + 4], a[b0 + 5]);
  uint32_t q3 = pack2(a[b0 + 6], a[b0 + 7]);
  uint32_t x0 = (uint32_t)__shfl_xor((int)q0, 32, 64);
  uint32_t x1 = (uint32_t)__shfl_xor((int)q1, 32, 64);
  uint32_t x2 = (uint32_t)__shfl_xor((int)q2, 32, 64);
  uint32_t x3 = (uint32_t)__shfl_xor((int)q3, 32, 64);
  uint32_t d0 = hf ? x2 : q0;
  uint32_t d1 = hf ? x3 : q1;
  uint32_t d2 = hf ? q2 : x0;
  uint32_t d3 = hf ? q3 : x1;
  return frag_from_u4(d0, d1, d2, d3);
}

// ---------------------------------------------------------------------------
// Prep: FRAGMENT-ORDERED packs (unchanged from R8-R12).
//  Wpack  [sec(3: q,k,v)][h(8)][kt(16)][lane(64)][i(8)] bf16
//  WoPack [h][kt][lane][i] bf16
//  Bpack  [type(4)][ai(2)][bi(2)][rb(4)][lane(64)][j(4)] f32
// ---------------------------------------------------------------------------
__global__ void prep_weights(const float* __restrict__ wqkv,
                             const float* __restrict__ wout,
                             const float* __restrict__ pos,
                             ushort* __restrict__ Wpack,
                             ushort* __restrict__ WoPack,
                             float* __restrict__ Bpack) {
  int id = blockIdx.x * 256 + threadIdx.x;
  if (id < 196608) {                       // 3*8*16*64*8
    int sec = id >> 16;
    int j = id & 65535;
    int h = j >> 13, kt = (j >> 9) & 15, lane = (j >> 3) & 63, i = j & 7;
    int n = h * 32 + (lane & 31);
    int k = kt * 16 + (lane >> 5) * 8 + i;
    float v = wqkv[k * 768 + sec * 256 + n];
    if (sec == 0) v *= QK_SCALE;
    Wpack[id] = __bfloat16_as_ushort(__float2bfloat16(v));
  } else if (id < 262144) {                // + 8*16*64*8
    int j = id - 196608;
    int h = j >> 13, kt = (j >> 9) & 15, lane = (j >> 3) & 63, i = j & 7;
    int n = h * 32 + (lane & 31);
    int k = kt * 16 + (lane >> 5) * 8 + i;
    WoPack[j] = __bfloat16_as_ushort(__float2bfloat16(wout[k * 256 + n]));
  } else if (id < 278528) {                // + 4*2*2*4*64*4
    int j = id - 262144;
    int type = j >> 12;
    int r12 = j & 4095;
    int ai = r12 >> 11, bi = (r12 >> 10) & 1, rb = (r12 >> 8) & 3;
    int lane = (r12 >> 2) & 63, jj = r12 & 3;
    int n = jj + 8 * rb + 4 * (lane >> 5) + 32 * ai;
    int m = (lane & 31) + 32 * bi;
    float v = pos[((n >> 3) - (m >> 3) + 7) * 15 + ((n & 7) - (m & 7) + 7)];
    bool ul = (m >= 32) != (n >= 32);
    bool lr = ((m & 7) >= 4) != ((n & 7) >= 4);
    if (((type & 2) && ul) || ((type & 1) && lr)) v = -1e30f;
    Bpack[j] = v;
  }
}

// ---------------------------------------------------------------------------
__global__ __launch_bounds__(512, 2) void swin_attn(
    const float* __restrict__ x, const float* __restrict__ bout,
    const ushort* __restrict__ Wpack, const ushort* __restrict__ WoPack,
    const float* __restrict__ Bpack, float* __restrict__ out) {
  // 32 KB union: phases 0-2 x-window bf16 (k-grouped, swizzled);
  // phases 3-4 O^T bf16 (same k-grouped slot layout, k = h*32+d).
  __shared__ uint4 lds[32 * 64];
  uint4*  ldsX = lds;
  ushort* ldsO = (ushort*)lds;

  const int bid = blockIdx.x;
  const int b  = bid >> 8;
  const int wy = (bid >> 4) & 15;
  const int wx = bid & 15;
  const int t    = threadIdx.x;
  const int lane = t & 63;
  const int h    = t >> 6;                 // wave id == head id
  const int l31  = lane & 31;
  const int hf   = lane >> 5;

  f32x16 zf;
  #pragma unroll
  for (int i = 0; i < 16; ++i) zf[i] = 0.0f;

  // ---- stage shifted x window -> LDS bf16 -------------------------------
  {
    int tok = t >> 3, kc = t & 7;
    int ty = tok >> 3, tx = tok & 7;
    int yy = (wy * 8 + ty + 4) & 127;      // roll(-4,-4) folded into read
    int xx = (wx * 8 + tx + 4) & 127;
    const float* xr = x + (((b * 128 + yy) * 128 + xx) << 8) + kc * 32;
    #pragma unroll
    for (int g = 0; g < 4; ++g) {
      float4 a = *(const float4*)(xr + g * 8);
      float4 c = *(const float4*)(xr + g * 8 + 4);
      uint4 w;
      w.x = pack2(a.x, a.y); w.y = pack2(a.z, a.w);
      w.z = pack2(c.x, c.y); w.w = pack2(c.z, c.w);
      int kg = kc * 4 + g;
      ldsX[(kg * 64 + tok) ^ kc] = w;      // kc == kg>>2
    }
  }
  __syncthreads();

  // Per-head fragment-ordered weight bases (1KB contiguous per wave-load).
  const ushort* wqp = Wpack + h * 8192;            // [kt][lane][8]
  const ushort* wkp = wqp + 65536;
  const ushort* wvp = wkp + 65536;

  // ---- pass Q: Q^T = Wq · X^T  (unroll 4: cap in-flight loads) ----------
  bf16x8 fQ[2][2];
  {
    f32x16 a0 = zf, a1 = zf;
    #pragma unroll 4
    for (int kt = 0; kt < 16; ++kt) {
      int kg = 2 * kt + hf;
      uint4 ux0 = ldsX[(kg * 64 + l31) ^ (kg >> 2)];
      uint4 ux1 = ldsX[(kg * 64 + 32 + l31) ^ (kg >> 2)];
      bf16x8 xf0 = frag_from_u4(ux0.x, ux0.y, ux0.z, ux0.w);
      bf16x8 xf1 = frag_from_u4(ux1.x, ux1.y, ux1.z, ux1.w);
      bf16x8 fw = *(const bf16x8*)(wqp + kt * 512 + lane * 8);
      a0 = MFMA32(fw, xf0, a0);  a1 = MFMA32(fw, xf1, a1);
    }
    #pragma unroll
    for (int kt = 0; kt < 2; ++kt) {
      fQ[0][kt] = makefrag(a0, kt, hf);
      fQ[1][kt] = makefrag(a1, kt, hf);
    }
  }

  // ---- pass K: K^T = Wk · X^T -------------------------------------------
  bf16x8 fK[2][2];
  {
    f32x16 a0 = zf, a1 = zf;
    #pragma unroll 4
    for (int kt = 0; kt < 16; ++kt) {
      int kg = 2 * kt + hf;
      uint4 ux0 = ldsX[(kg * 64 + l31) ^ (kg >> 2)];
      uint4 ux1 = ldsX[(kg * 64 + 32 + l31) ^ (kg >> 2)];
      bf16x8 xf0 = frag_from_u4(ux0.x, ux0.y, ux0.z, ux0.w);
      bf16x8 xf1 = frag_from_u4(ux1.x, ux1.y, ux1.z, ux1.w);
      bf16x8 fw = *(const bf16x8*)(wkp + kt * 512 + lane * 8);
      a0 = MFMA32(fw, xf0, a0);  a1 = MFMA32(fw, xf1, a1);
    }
    #pragma unroll
    for (int kt = 0; kt < 2; ++kt) {
      fK[0][kt] = makefrag(a0, kt, hf);
      fK[1][kt] = makefrag(a1, kt, hf);
    }
  }

  // ---- bi-sequential S/softmax/P-conversion (AGPR peak 32) --------------
  const float* Bp = Bpack + ((((wy == 15) ? 2 : 0) | ((wx == 15) ? 1 : 0)) << 12);
  bf16x8 pf[2][4];
  float ri[2];
  #pragma unroll
  for (int bi = 0; bi < 2; ++bi) {
    f32x16 s0, s1;                         // S^T key-tiles ai=0,1 for this bi
    #pragma unroll
    for (int rb = 0; rb < 4; ++rb) {
      float4 f0 = *(const float4*)(Bp + ((bi * 4 + rb) * 64 + lane) * 4);
      float4 f1 = *(const float4*)(Bp + (((2 + bi) * 4 + rb) * 64 + lane) * 4);
      s0[rb * 4 + 0] = f0.x; s0[rb * 4 + 1] = f0.y;
      s0[rb * 4 + 2] = f0.z; s0[rb * 4 + 3] = f0.w;
      s1[rb * 4 + 0] = f1.x; s1[rb * 4 + 1] = f1.y;
      s1[rb * 4 + 2] = f1.z; s1[rb * 4 + 3] = f1.w;
    }
    #pragma unroll
    for (int kt = 0; kt < 2; ++kt) {
      s0 = MFMA32(fK[0][kt], fQ[bi][kt], s0);
      s1 = MFMA32(fK[1][kt], fQ[bi][kt], s1);
    }
    float mx = -3e38f;
    #pragma unroll
    for (int r = 0; r < 16; ++r) mx = fmaxf(mx, fmaxf(s0[r], s1[r]));
    mx = fmaxf(mx, __shfl_xor(mx, 32, 64));
    float sum = 0.0f;
    #pragma unroll
    for (int r = 0; r < 16; ++r) {
      float p0 = exp2f((s0[r] - mx) * LOG2E);
      float p1 = exp2f((s1[r] - mx) * LOG2E);
      s0[r] = p0; s1[r] = p1;
      sum += p0 + p1;
    }
    sum += __shfl_xor(sum, 32, 64);
    ri[bi] = 1.0f / sum;                   // deferred to ot scale
    #pragma unroll
    for (int kt = 0; kt < 2; ++kt) {
      pf[bi][kt]     = makefrag(s0, kt, hf);
      pf[bi][2 + kt] = makefrag(s1, kt, hf);
    }
  }

  // ---- pass V: V = X · Wv (fQ/fK dead) ----------------------------------
  bf16x8 fV[2][2];
  {
    f32x16 a0 = zf, a1 = zf;
    #pragma unroll 4
    for (int kt = 0; kt < 16; ++kt) {
      int kg = 2 * kt + hf;
      uint4 ux0 = ldsX[(kg * 64 + l31) ^ (kg >> 2)];
      uint4 ux1 = ldsX[(kg * 64 + 32 + l31) ^ (kg >> 2)];
      bf16x8 xf0 = frag_from_u4(ux0.x, ux0.y, ux0.z, ux0.w);
      bf16x8 xf1 = frag_from_u4(ux1.x, ux1.y, ux1.z, ux1.w);
      bf16x8 fw = *(const bf16x8*)(wvp + kt * 512 + lane * 8);
      a0 = MFMA32(xf0, fw, a0);  a1 = MFMA32(xf1, fw, a1);
    }
    #pragma unroll
    for (int kt = 0; kt < 2; ++kt) {
      fV[0][kt] = makefrag(a0, kt, hf);
      fV[1][kt] = makefrag(a1, kt, hf);
    }
  }

  // ---- O^T = V^T · P^T  (ot[bi]: row=d, col=query token) ----------------
  f32x16 ot[2];
  ot[0] = zf; ot[1] = zf;
  #pragma unroll
  for (int jt = 0; jt < 4; ++jt) {
    bf16x8 aV = fV[jt >> 1][jt & 1];
    ot[0] = MFMA32(aV, pf[0][jt], ot[0]);
    ot[1] = MFMA32(aV, pf[1][jt], ot[1]);
  }
  #pragma unroll
  for (int bi = 0; bi < 2; ++bi)
    #pragma unroll
    for (int r = 0; r < 16; ++r) ot[bi][r] *= ri[bi];

  // all waves must be done reading ldsX before ldsO overwrites the union
  __syncthreads();

  // ---- O^T -> LDS bf16 (k = h*32 + d, k-grouped slots) ------------------
  {
    #pragma unroll
    for (int bi = 0; bi < 2; ++bi) {
      int tok = bi * 32 + l31;
      #pragma unroll
      for (int g = 0; g < 4; ++g) {
        int kg = h * 4 + g;                // d = 8g + 4hf + 0..3
        uint2 wv2;
        wv2.x = pack2(ot[bi][4 * g + 0], ot[bi][4 * g + 1]);
        wv2.y = pack2(ot[bi][4 * g + 2], ot[bi][4 * g + 3]);
        *(uint2*)&ldsO[(kg * 64 + tok) * 8 + 4 * hf] = wv2;
      }
    }
  }
  __syncthreads();

  // ---- out-proj: out^T = W_out^T · O^T  (wave h -> out cols h*32..+31) --
  const ushort* wop = WoPack + h * 8192;
  f32x16 u[2];
  u[0] = zf; u[1] = zf;
  #pragma unroll 4
  for (int kt = 0; kt < 16; ++kt) {
    int kg = 2 * kt + hf;
    bf16x8 wa = *(const bf16x8*)(wop + kt * 512 + lane * 8);
    bf16x8 b0 = *(const bf16x8*)&ldsO[(kg * 64 + l31) * 8];
    bf16x8 b1 = *(const bf16x8*)&ldsO[(kg * 64 + 32 + l31) * 8];
    u[0] = MFMA32(wa, b0, u[0]);
    u[1] = MFMA32(wa, b1, u[1]);
  }

  // ---- epilogue: + b_out, write fp32 with roll(+4,+4) folded in ---------
  #pragma unroll
  for (int tt = 0; tt < 2; ++tt) {
    int tok = 32 * tt + l31;
    int ty = tok >> 3, tx = tok & 7;
    int yy = (wy * 8 + ty + 4) & 127;
    int xx = (wx * 8 + tx + 4) & 127;
    float* ob = out + (((b * 128 + yy) * 128 + xx) << 8);
    #pragma unroll
    for (int g = 0; g < 4; ++g) {
      int c0 = h * 32 + 8 * g + 4 * hf;
      float4 bo = *(const float4*)(bout + c0);
      float4 v;
      v.x = (tt ? u[1][4 * g + 0] : u[0][4 * g + 0]) + bo.x;
      v.y = (tt ? u[1][4 * g + 1] : u[0][4 * g + 1]) + bo.y;
      v.z = (tt ? u[1][4 * g + 2] : u[0][4 * g + 2]) + bo.z;
      v.w = (tt ? u[1][4 * g + 3] : u[0][4 * g + 3]) + bo.w;
      *(float4*)(ob + c0) = v;
    }
  }
}

// ---------------------------------------------------------------------------
extern "C" void kernel_launch(void* const* d_in, const int* in_sizes, int n_in,
                              void* d_out, int out_size, void* d_ws, size_t ws_size,
                              hipStream_t stream) {
  const float* x    = (const float*)d_in[0];
  const float* wqkv = (const float*)d_in[1];
  const float* pos  = (const float*)d_in[2];
  const float* wout = (const float*)d_in[3];
  const float* bout = (const float*)d_in[4];

  ushort* Wpack  = (ushort*)d_ws;                     // [3][8][16][64][8] bf16
  ushort* WoPack = Wpack + 196608;                    // [8][16][64][8] bf16
  float*  Bpack  = (float*)((char*)d_ws + 524288);    // [4][2][2][4][64][4] f32

  prep_weights<<<1088, 256, 0, stream>>>(wqkv, wout, pos, Wpack, WoPack, Bpack);
  swin_attn<<<2048, 512, 0, stream>>>(x, bout, Wpack, WoPack, Bpack, (float*)d_out);
}